// Round 6
// baseline (193.844 us; speedup 1.0000x reference)
//
#include <hip/hip_runtime.h>

#define CAR 8
#define SROW 520   // CAR + 64*CAR
#define HID 256
#define EOUT 257
#define XPAD 288   // padded Q-input row: 8 self + 257 enc + pad, 9 k-steps of 32
#define ADIM 30

typedef __attribute__((ext_vector_type(8))) short sh8;
typedef __attribute__((ext_vector_type(4))) float f32x4;

__device__ __forceinline__ short f2bf(float f) {
  unsigned u = __builtin_bit_cast(unsigned, f);
  u += 0x7fffu + ((u >> 16) & 1u);   // RNE
  return (short)(u >> 16);
}
// pack two fp32 -> packed bf16x2 (RNE)
__device__ __forceinline__ unsigned f2bf2(float a, float b) {
  unsigned ua = __builtin_bit_cast(unsigned, a);
  ua += 0x7fffu + ((ua >> 16) & 1u);
  unsigned ub = __builtin_bit_cast(unsigned, b);
  ub += 0x7fffu + ((ub >> 16) & 1u);
  return __builtin_amdgcn_perm(ub, ua, 0x07060302);  // [a.hi16, b.hi16]
}

// ---------------------------------------------------------------------------
// Prep: swizzle all weights to bf16 MFMA fragments.
// frag convention (16x16x32): A[m=lane&15][k=quad*8+j], B[k=quad*8+j][n=lane&15],
// C/D: row(m)=quad*4+reg, col(n)=lane&15.
// w1f : W1^T as A  [16 mt][64][8]                     (8192)
// w2f : W2  as B   [8 ks][17 nt][64][8]               (69632)  stride/ks = 8704!
// w3f : Qw1 as B   [9 ks][16 nt][64][8], k=X-row idx  (73728)
// wq2f: Qw2 as B   [8 ks][2 nt][64][8]                (8192)
// ---------------------------------------------------------------------------
__global__ void k_prep(const float* __restrict__ W1, const float* __restrict__ W2,
                       const float* __restrict__ Qw1, const float* __restrict__ Qw2,
                       short* __restrict__ w1f, short* __restrict__ w2f,
                       short* __restrict__ w3f, short* __restrict__ wq2f) {
  int idx = blockIdx.x * 256 + threadIdx.x;
  if (idx < 8192) {                         // W1^T as A: A[m=hid][k=c]
    int mt = idx >> 9, r = idx & 511, lane = r >> 3, j = r & 7;
    int quad = lane >> 4, m = lane & 15;
    float v = (quad == 0) ? W1[j * HID + mt * 16 + m] : 0.0f;
    w1f[idx] = f2bf(v);
    return;
  }
  int i2 = idx - 8192;
  if (i2 < 69632) {                         // W2 as B (ks stride = 17*512 = 8704)
    int ks = i2 / 8704, r = i2 % 8704;
    int nt = r >> 9, r2 = r & 511, lane = r2 >> 3, j = r2 & 7;
    int quad = lane >> 4, m = lane & 15;
    int k = ks * 32 + quad * 8 + j, n = nt * 16 + m;
    float v = (n < EOUT) ? W2[k * EOUT + n] : 0.0f;
    w2f[i2] = f2bf(v);
    return;
  }
  int i3 = i2 - 69632;
  if (i3 < 73728) {                         // Qw1 as B (k indexes padded X row)
    int ks = i3 >> 13, r = i3 & 8191;
    int nt = r >> 9, r2 = r & 511, lane = r2 >> 3, j = r2 & 7;
    int quad = lane >> 4, m = lane & 15;
    int k = ks * 32 + quad * 8 + j, n = nt * 16 + m;
    float v = (k < 265) ? Qw1[k * HID + n] : 0.0f;
    w3f[i3] = f2bf(v);
    return;
  }
  int i4 = i3 - 73728;
  if (i4 < 8192) {                          // Qw2 as B
    int ks = i4 >> 10, r = i4 & 1023;
    int nt = r >> 9, r2 = r & 511, lane = r2 >> 3, j = r2 & 7;
    int quad = lane >> 4, m = lane & 15;
    int k = ks * 32 + quad * 8 + j, n = nt * 16 + m;
    float v = (n < ADIM) ? Qw2[k * ADIM + n] : 0.0f;
    wq2f[i4] = f2bf(v);
  }
}

// ---------------------------------------------------------------------------
// Fully-fused kernel: encoder + pool + Q-head, NB=2 batch elems per block.
// Phases 1-3 as R5. Then (LDS reused): X rows -> xq[2][288] in LDS,
// GEMM1 X@Qw1 (wave w: nt 4w..4w+3, M=2 live rows of 16), H->LDS,
// GEMM2 H@Qw2 on wave 0, direct store to out. No so288 global round-trip,
// no separate k_q kernel.
// ---------------------------------------------------------------------------
__global__ __launch_bounds__(256, 2)
void k_enc(const float* __restrict__ s, const short* __restrict__ w1f,
           const float* __restrict__ b1, const short* __restrict__ w2f,
           const float* __restrict__ b2, const short* __restrict__ w3f,
           const float* __restrict__ Qb1, const short* __restrict__ wq2f,
           const float* __restrict__ Qb2, float* __restrict__ out, int B) {
  __shared__ __align__(16) short hlds[2][16384];  // 2 x (64 agents x 256 hid) bf16
  __shared__ float ninvp[4];
  float* xq = (float*)&hlds[0][0];     // overlay after phase 2: [2][288] X rows
  float* Hq = xq + 2 * XPAD;           // [2][256] hidden rows

  const int tid = threadIdx.x;
  const int w = tid >> 6, lane = tid & 63;
  const int q = lane >> 4, m = lane & 15;
  const int be = w >> 1, half = w & 1;
  const size_t b0 = 2 * (size_t)blockIdx.x;
  int bg = (int)b0 + be; if (bg >= B) bg = B - 1;

  // ---- phase 1: h = relu(surr@W1+b1), masked, bf16 -> hlds (A-frag order) ----
  const float* srow0 = s + (size_t)bg * SROW + CAR;
  int4 pk = {0, 0, 0, 0};
  bool inv = false;
  if (lane < 32) {                   // agent (local in be) = 32*half + lane
    const float* sr = srow0 + (half * 32 + lane) * CAR;
    float4 f0 = ((const float4*)sr)[0], f1 = ((const float4*)sr)[1];
    inv = (f0.x == -1.f) | (f0.y == -1.f) | (f0.z == -1.f) | (f0.w == -1.f) |
          (f1.x == -1.f) | (f1.y == -1.f) | (f1.z == -1.f) | (f1.w == -1.f);
    pk.x = (int)f2bf2(f0.x, f0.y); pk.y = (int)f2bf2(f0.z, f0.w);
    pk.z = (int)f2bf2(f1.x, f1.y); pk.w = (int)f2bf2(f1.z, f1.w);
  }
  const float vflag = inv ? 0.f : 1.f;
  unsigned long long bal = __ballot(inv);
  if (lane == 0) ninvp[w] = (float)__popcll(bal);

  int4 p0, p1;
  p0.x = __shfl(pk.x, m, 64);      p0.y = __shfl(pk.y, m, 64);
  p0.z = __shfl(pk.z, m, 64);      p0.w = __shfl(pk.w, m, 64);
  p1.x = __shfl(pk.x, 16 + m, 64); p1.y = __shfl(pk.y, 16 + m, 64);
  p1.z = __shfl(pk.z, 16 + m, 64); p1.w = __shfl(pk.w, 16 + m, 64);
  const float vv0 = __shfl(vflag, m, 64);
  const float vv1 = __shfl(vflag, 16 + m, 64);
  if (q != 0) { p0.x = p0.y = p0.z = p0.w = 0; p1.x = p1.y = p1.z = p1.w = 0; }
  sh8 bs0 = __builtin_bit_cast(sh8, p0);
  sh8 bs1 = __builtin_bit_cast(sh8, p1);

  const int T0 = half * 2, T1 = half * 2 + 1;
#pragma unroll
  for (int mt = 0; mt < 16; ++mt) {
    sh8 af = *(const sh8*)(w1f + (mt * 64 + lane) * 8);
    f32x4 z = {0.f, 0.f, 0.f, 0.f};
    f32x4 c0 = __builtin_amdgcn_mfma_f32_16x16x32_bf16(af, bs0, z, 0, 0, 0);
    f32x4 c1 = __builtin_amdgcn_mfma_f32_16x16x32_bf16(af, bs1, z, 0, 0, 0);
    const int hidb = mt * 16 + q * 4;
    float4 b1v = *(const float4*)(b1 + hidb);
    const int ks = hidb >> 5, qB = (hidb >> 3) & 3, js = hidb & 7;
    uint2 k0, k1;
    k0.x = f2bf2(fmaxf(c0[0] + b1v.x, 0.f) * vv0, fmaxf(c0[1] + b1v.y, 0.f) * vv0);
    k0.y = f2bf2(fmaxf(c0[2] + b1v.z, 0.f) * vv0, fmaxf(c0[3] + b1v.w, 0.f) * vv0);
    k1.x = f2bf2(fmaxf(c1[0] + b1v.x, 0.f) * vv1, fmaxf(c1[1] + b1v.y, 0.f) * vv1);
    k1.y = f2bf2(fmaxf(c1[2] + b1v.z, 0.f) * vv1, fmaxf(c1[3] + b1v.w, 0.f) * vv1);
    *(uint2*)(&hlds[be][((T0 * 8 + ks) * 64 + qB * 16 + m) * 8 + js]) = k0;
    *(uint2*)(&hlds[be][((T1 * 8 + ks) * 64 + qB * 16 + m) * 8 + js]) = k1;
  }
  __syncthreads();

  // ---- phase 2: enc = h @ W2 (K=256 unrolled, Bf double-buffered) ----
  int tiles[5];
#pragma unroll
  for (int i = 0; i < 4; ++i) tiles[i] = 4 * w + i;
  tiles[4] = (w == 0) ? 16 : 4 * w;          // dup for w!=0 (uniform code)

  f32x4 acc[4][5][2];
#pragma unroll
  for (int mt = 0; mt < 4; ++mt)
#pragma unroll
    for (int i = 0; i < 5; ++i)
#pragma unroll
      for (int e = 0; e < 2; ++e) {
        f32x4 z = {0.f, 0.f, 0.f, 0.f};
        acc[mt][i][e] = z;
      }

  sh8 Bf[5];
#pragma unroll
  for (int i = 0; i < 5; ++i)
    Bf[i] = *(const sh8*)(w2f + ((0 * 17 + tiles[i]) * 64 + lane) * 8);

#pragma unroll
  for (int ks = 0; ks < 8; ++ks) {
    sh8 Bn[5];
    if (ks < 7) {
#pragma unroll
      for (int i = 0; i < 5; ++i)
        Bn[i] = *(const sh8*)(w2f + (((ks + 1) * 17 + tiles[i]) * 64 + lane) * 8);
    }
#pragma unroll
    for (int e = 0; e < 2; ++e) {
      sh8 A[4];
#pragma unroll
      for (int mt = 0; mt < 4; ++mt)
        A[mt] = *(const sh8*)(&hlds[e][((mt * 8 + ks) * 64 + lane) * 8]);
#pragma unroll
      for (int i = 0; i < 5; ++i)
#pragma unroll
        for (int mt = 0; mt < 4; ++mt)
          acc[mt][i][e] = __builtin_amdgcn_mfma_f32_16x16x32_bf16(A[mt], Bf[i], acc[mt][i][e], 0, 0, 0);
    }
    if (ks < 7) {
#pragma unroll
      for (int i = 0; i < 5; ++i) Bf[i] = Bn[i];
    }
  }
  __syncthreads();   // all waves done reading hlds; xq/Hq overlay becomes safe

  // ---- phase 3: relu+pool -> xq rows in LDS ----
  const float ninv[2] = {ninvp[0] + ninvp[1], ninvp[2] + ninvp[3]};
#pragma unroll
  for (int i = 0; i < 5; ++i) {
    if (i == 4 && w != 0) continue;          // dup tile: no output
    const int col = tiles[i] * 16 + m;       // 0..271
    const float b2c = (col < EOUT) ? b2[col] : 0.f;
    const float rb2 = fmaxf(b2c, 0.f);
#pragma unroll
    for (int e = 0; e < 2; ++e) {
      float ssum = 0.f;
#pragma unroll
      for (int mt = 0; mt < 4; ++mt)
#pragma unroll
        for (int r = 0; r < 4; ++r)
          ssum += fmaxf(acc[mt][i][e][r] + b2c, 0.f);
      ssum += __shfl_xor(ssum, 16, 64);
      ssum += __shfl_xor(ssum, 32, 64);
      ssum -= ninv[e] * rb2;                 // pad cols: b2c=0 -> 0
      if (q == 0)
        xq[e * XPAD + CAR + col] = ssum;
    }
  }
  if (w == 1 || w == 2) {                    // self-state + tail pad per be
    const int e = w - 1;
    size_t rr = b0 + e; if (rr >= (size_t)B) rr = B - 1;
    if (lane < CAR)       xq[e * XPAD + lane] = s[rr * SROW + lane];
    else if (lane < 16)   xq[e * XPAD + 280 + (lane - 8)] = 0.f;
  }
  __syncthreads();

  // ---- phase 4: GEMM1  X(2x288) @ Qw1 -> Hq(2x256) ----
  f32x4 aq[4];
#pragma unroll
  for (int i = 0; i < 4; ++i) {
    f32x4 z = {0.f, 0.f, 0.f, 0.f};
    aq[i] = z;
  }
#pragma unroll
  for (int ks = 0; ks < 9; ++ks) {
    const float* xp = xq + (m & 1) * XPAD + ks * 32 + q * 8;   // rows 0/1 dup'd
    float4 xa = ((const float4*)xp)[0], xb = ((const float4*)xp)[1];
    int4 t = {(int)f2bf2(xa.x, xa.y), (int)f2bf2(xa.z, xa.w),
              (int)f2bf2(xb.x, xb.y), (int)f2bf2(xb.z, xb.w)};
    sh8 A = __builtin_bit_cast(sh8, t);
#pragma unroll
    for (int i = 0; i < 4; ++i) {
      sh8 Bq = *(const sh8*)(w3f + ((ks * 16 + 4 * w + i) * 64 + lane) * 8);
      aq[i] = __builtin_amdgcn_mfma_f32_16x16x32_bf16(A, Bq, aq[i], 0, 0, 0);
    }
  }
  if (q == 0) {                       // C rows 0,1 (be 0,1) live in q0 regs 0,1
#pragma unroll
    for (int i = 0; i < 4; ++i) {
      const int hcol = (4 * w + i) * 16 + m;
      const float bq = Qb1[hcol];
      Hq[0 * HID + hcol] = fmaxf(aq[i][0] + bq, 0.f);
      Hq[1 * HID + hcol] = fmaxf(aq[i][1] + bq, 0.f);
    }
  }
  __syncthreads();

  // ---- phase 5: GEMM2  H(2x256) @ Qw2 -> out (wave 0 only) ----
  if (w == 0) {
    f32x4 a2[2];
#pragma unroll
    for (int nt = 0; nt < 2; ++nt) {
      f32x4 z = {0.f, 0.f, 0.f, 0.f};
      a2[nt] = z;
    }
#pragma unroll
    for (int ks = 0; ks < 8; ++ks) {
      const float* hp = Hq + (m & 1) * HID + ks * 32 + q * 8;
      float4 ha = ((const float4*)hp)[0], hb = ((const float4*)hp)[1];
      int4 t = {(int)f2bf2(ha.x, ha.y), (int)f2bf2(ha.z, ha.w),
                (int)f2bf2(hb.x, hb.y), (int)f2bf2(hb.z, hb.w)};
      sh8 A2 = __builtin_bit_cast(sh8, t);
#pragma unroll
      for (int nt = 0; nt < 2; ++nt) {
        sh8 Bq = *(const sh8*)(wq2f + ((ks * 2 + nt) * 64 + lane) * 8);
        a2[nt] = __builtin_amdgcn_mfma_f32_16x16x32_bf16(A2, Bq, a2[nt], 0, 0, 0);
      }
    }
    if (q == 0) {
#pragma unroll
      for (int nt = 0; nt < 2; ++nt) {
        const int act = nt * 16 + m;
        if (act < ADIM) {
          const float bq = Qb2[act];
#pragma unroll
          for (int r = 0; r < 2; ++r) {      // C row r = batch elem b0+r
            if (b0 + r < (size_t)B)
              out[(b0 + r) * ADIM + act] = a2[nt][r] + bq;
          }
        }
      }
    }
  }
}

extern "C" void kernel_launch(void* const* d_in, const int* in_sizes, int n_in,
                              void* d_out, int out_size, void* d_ws, size_t ws_size,
                              hipStream_t stream) {
  const float* s   = (const float*)d_in[0];
  const float* W1  = (const float*)d_in[1];
  const float* b1  = (const float*)d_in[2];
  const float* W2  = (const float*)d_in[3];
  const float* b2  = (const float*)d_in[4];
  const float* Qw1 = (const float*)d_in[5];
  const float* Qb1 = (const float*)d_in[6];
  const float* Qw2 = (const float*)d_in[7];
  const float* Qb2 = (const float*)d_in[8];
  float* out = (float*)d_out;
  const int B = in_sizes[0] / SROW;

  // ws: [w1f 8192][w2f 69632][w3f 73728][wq2f 8192] bf16
  char* wsb = (char*)d_ws;
  short* w1f  = (short*)wsb;
  short* w2f  = (short*)(wsb + 8192 * 2);
  short* w3f  = (short*)(wsb + (8192 + 69632) * 2);
  short* wq2f = (short*)(wsb + (8192 + 69632 + 73728) * 2);

  const int prep_elems = 8192 + 69632 + 73728 + 8192;
  k_prep<<<(prep_elems + 255) / 256, 256, 0, stream>>>(W1, W2, Qw1, Qw2,
                                                       w1f, w2f, w3f, wq2f);
  k_enc<<<(B + 1) / 2, 256, 0, stream>>>(s, w1f, b1, w2f, b2,
                                         w3f, Qb1, wq2f, Qb2, out, B);
}

// Round 7
// 161.111 us; speedup vs baseline: 1.2032x; 1.2032x over previous
//
#include <hip/hip_runtime.h>

#define CAR 8
#define SROW 520   // CAR + 64*CAR
#define HID 256
#define EOUT 257
#define XPAD 288   // padded Q-input row: 8 self + 257 enc + pad, 9 k-steps of 32
#define ADIM 30

typedef __attribute__((ext_vector_type(8))) short sh8;
typedef __attribute__((ext_vector_type(4))) float f32x4;

__device__ __forceinline__ short f2bf(float f) {
  unsigned u = __builtin_bit_cast(unsigned, f);
  u += 0x7fffu + ((u >> 16) & 1u);   // RNE
  return (short)(u >> 16);
}
// pack two fp32 -> packed bf16x2 (RNE, 5 VALU)
__device__ __forceinline__ unsigned f2bf2(float a, float b) {
  unsigned ua = __builtin_bit_cast(unsigned, a);
  ua += 0x7fffu + ((ua >> 16) & 1u);
  unsigned ub = __builtin_bit_cast(unsigned, b);
  ub += 0x7fffu + ((ub >> 16) & 1u);
  return __builtin_amdgcn_perm(ub, ua, 0x07060302);  // [a.hi16 | b.hi16]
}
// pack two fp32 -> packed bf16x2 (TRUNC, 1 VALU) — used for h staging only
__device__ __forceinline__ unsigned pkt(float a, float b) {
  return __builtin_amdgcn_perm(__builtin_bit_cast(unsigned, b),
                               __builtin_bit_cast(unsigned, a), 0x07060302);
}

// ---------------------------------------------------------------------------
// Prep: swizzle all weights to bf16 MFMA fragments.
// frag convention (16x16x32): A[m=lane&15][k=quad*8+j], B[k=quad*8+j][n=lane&15],
// C/D: row(m)=quad*4+reg, col(n)=lane&15.
// w1f : [W1;b1]^T as A [16 mt][64][8]  k=0..7 -> W1 row, k=8 -> b1   (8192)
// w2f : W2  as B   [8 ks][17 nt][64][8]               (69632)  stride/ks = 8704!
// w3f : Qw1 as B   [9 ks][16 nt][64][8], k=X-row idx  (73728)
// wq2f: Qw2 as B   [8 ks][2 nt][64][8]                (8192)
// ---------------------------------------------------------------------------
__global__ void k_prep(const float* __restrict__ W1, const float* __restrict__ b1,
                       const float* __restrict__ W2,
                       const float* __restrict__ Qw1, const float* __restrict__ Qw2,
                       short* __restrict__ w1f, short* __restrict__ w2f,
                       short* __restrict__ w3f, short* __restrict__ wq2f) {
  int idx = blockIdx.x * 256 + threadIdx.x;
  if (idx < 8192) {                         // [W1;b1]^T as A
    int mt = idx >> 9, r = idx & 511, lane = r >> 3, j = r & 7;
    int quad = lane >> 4, m = lane & 15;
    int hid = mt * 16 + m;
    float v = (quad == 0) ? W1[j * HID + hid]
            : (quad == 1 && j == 0) ? b1[hid] : 0.0f;   // k=8 row = b1
    w1f[idx] = f2bf(v);
    return;
  }
  int i2 = idx - 8192;
  if (i2 < 69632) {                         // W2 as B (ks stride = 17*512 = 8704)
    int ks = i2 / 8704, r = i2 % 8704;
    int nt = r >> 9, r2 = r & 511, lane = r2 >> 3, j = r2 & 7;
    int quad = lane >> 4, m = lane & 15;
    int k = ks * 32 + quad * 8 + j, n = nt * 16 + m;
    float v = (n < EOUT) ? W2[k * EOUT + n] : 0.0f;
    w2f[i2] = f2bf(v);
    return;
  }
  int i3 = i2 - 69632;
  if (i3 < 73728) {                         // Qw1 as B (k indexes padded X row)
    int ks = i3 >> 13, r = i3 & 8191;
    int nt = r >> 9, r2 = r & 511, lane = r2 >> 3, j = r2 & 7;
    int quad = lane >> 4, m = lane & 15;
    int k = ks * 32 + quad * 8 + j, n = nt * 16 + m;
    float v = (k < 265) ? Qw1[k * HID + n] : 0.0f;
    w3f[i3] = f2bf(v);
    return;
  }
  int i4 = i3 - 73728;
  if (i4 < 8192) {                          // Qw2 as B
    int ks = i4 >> 10, r = i4 & 1023;
    int nt = r >> 9, r2 = r & 511, lane = r2 >> 3, j = r2 & 7;
    int quad = lane >> 4, m = lane & 15;
    int k = ks * 32 + quad * 8 + j, n = nt * 16 + m;
    float v = (n < ADIM) ? Qw2[k * ADIM + n] : 0.0f;
    wq2f[i4] = f2bf(v);
  }
}

// ---------------------------------------------------------------------------
// K1: fused encoder + pool, NB=2 batch elems per block, 4 waves.
// Phase 1: h = relu([surr,1]@[W1;b1]) with mask folded into the B operand
//   (invalid agent columns zeroed incl. the k=8 1.0); trunc bf16 pack -> hlds.
// Phase 2: wave 0: 5 N-tiles {0..3,16}; waves 1-3: 4 tiles (no dup) — split
//   wave-uniform branches keep full unroll + load hoisting.
// Phase 3: relu+pool epilogue -> so288 rows.
// ---------------------------------------------------------------------------
__global__ __launch_bounds__(256, 2)
void k_enc(const float* __restrict__ s, const short* __restrict__ w1f,
           const short* __restrict__ w2f, const float* __restrict__ b2,
           float* __restrict__ so288, int B) {
  __shared__ __align__(16) short hlds[2][16384];  // 2 x (64 agents x 256 hid) bf16
  __shared__ float ninvp[4];

  const int tid = threadIdx.x;
  const int w = tid >> 6, lane = tid & 63;
  const int q = lane >> 4, m = lane & 15;
  const int be = w >> 1, half = w & 1;
  const size_t b0 = 2 * (size_t)blockIdx.x;
  int bg = (int)b0 + be; if (bg >= B) bg = B - 1;

  // ---- phase 1 ----
  const float* srow0 = s + (size_t)bg * SROW + CAR;
  int4 pk = {0, 0, 0, 0};
  bool inv = false;
  if (lane < 32) {                   // agent (local in be) = 32*half + lane
    const float* sr = srow0 + (half * 32 + lane) * CAR;
    float4 f0 = ((const float4*)sr)[0], f1 = ((const float4*)sr)[1];
    inv = (f0.x == -1.f) | (f0.y == -1.f) | (f0.z == -1.f) | (f0.w == -1.f) |
          (f1.x == -1.f) | (f1.y == -1.f) | (f1.z == -1.f) | (f1.w == -1.f);
    if (!inv) {                      // mask folded at source
      pk.x = (int)f2bf2(f0.x, f0.y); pk.y = (int)f2bf2(f0.z, f0.w);
      pk.z = (int)f2bf2(f1.x, f1.y); pk.w = (int)f2bf2(f1.z, f1.w);
    }
  }
  const float vflag = inv ? 0.f : 1.f;
  unsigned long long bal = __ballot(inv);
  if (lane == 0) ninvp[w] = (float)__popcll(bal);

  int4 p0, p1;
  p0.x = __shfl(pk.x, m, 64);      p0.y = __shfl(pk.y, m, 64);
  p0.z = __shfl(pk.z, m, 64);      p0.w = __shfl(pk.w, m, 64);
  p1.x = __shfl(pk.x, 16 + m, 64); p1.y = __shfl(pk.y, 16 + m, 64);
  p1.z = __shfl(pk.z, 16 + m, 64); p1.w = __shfl(pk.w, 16 + m, 64);
  const float vv0 = __shfl(vflag, m, 64);
  const float vv1 = __shfl(vflag, 16 + m, 64);
  if (q == 1) {                      // k=8 constant-1 column (masked)
    p0.x = (vv0 != 0.f) ? 0x3f80 : 0; p0.y = p0.z = p0.w = 0;
    p1.x = (vv1 != 0.f) ? 0x3f80 : 0; p1.y = p1.z = p1.w = 0;
  } else if (q >= 2) {
    p0.x = p0.y = p0.z = p0.w = 0;   p1.x = p1.y = p1.z = p1.w = 0;
  }
  sh8 bs0 = __builtin_bit_cast(sh8, p0);
  sh8 bs1 = __builtin_bit_cast(sh8, p1);

  const int T0 = half * 2, T1 = half * 2 + 1;
#pragma unroll
  for (int mt = 0; mt < 16; ++mt) {
    sh8 af = *(const sh8*)(w1f + (mt * 64 + lane) * 8);
    f32x4 z = {0.f, 0.f, 0.f, 0.f};
    f32x4 c0 = __builtin_amdgcn_mfma_f32_16x16x32_bf16(af, bs0, z, 0, 0, 0);
    f32x4 c1 = __builtin_amdgcn_mfma_f32_16x16x32_bf16(af, bs1, z, 0, 0, 0);
    const int hidb = mt * 16 + q * 4;
    const int ks = hidb >> 5, qB = (hidb >> 3) & 3, js = hidb & 7;
    uint2 k0, k1;
    k0.x = pkt(fmaxf(c0[0], 0.f), fmaxf(c0[1], 0.f));
    k0.y = pkt(fmaxf(c0[2], 0.f), fmaxf(c0[3], 0.f));
    k1.x = pkt(fmaxf(c1[0], 0.f), fmaxf(c1[1], 0.f));
    k1.y = pkt(fmaxf(c1[2], 0.f), fmaxf(c1[3], 0.f));
    *(uint2*)(&hlds[be][((T0 * 8 + ks) * 64 + qB * 16 + m) * 8 + js]) = k0;
    *(uint2*)(&hlds[be][((T1 * 8 + ks) * 64 + qB * 16 + m) * 8 + js]) = k1;
  }
  __syncthreads();

  // ---- phase 2 ----
  f32x4 acc[4][5][2];
#pragma unroll
  for (int mt = 0; mt < 4; ++mt)
#pragma unroll
    for (int i = 0; i < 5; ++i)
#pragma unroll
      for (int e = 0; e < 2; ++e) {
        f32x4 z = {0.f, 0.f, 0.f, 0.f};
        acc[mt][i][e] = z;
      }

  if (w == 0) {                      // 5 tiles {0,1,2,3,16}
    sh8 Bf[5];
#pragma unroll
    for (int i = 0; i < 5; ++i) {
      const int t = (i < 4) ? i : 16;
      Bf[i] = *(const sh8*)(w2f + ((0 * 17 + t) * 64 + lane) * 8);
    }
#pragma unroll
    for (int ks = 0; ks < 8; ++ks) {
      sh8 Bn[5];
      if (ks < 7) {
#pragma unroll
        for (int i = 0; i < 5; ++i) {
          const int t = (i < 4) ? i : 16;
          Bn[i] = *(const sh8*)(w2f + (((ks + 1) * 17 + t) * 64 + lane) * 8);
        }
      }
#pragma unroll
      for (int e = 0; e < 2; ++e) {
        sh8 A[4];
#pragma unroll
        for (int mt = 0; mt < 4; ++mt)
          A[mt] = *(const sh8*)(&hlds[e][((mt * 8 + ks) * 64 + lane) * 8]);
#pragma unroll
        for (int i = 0; i < 5; ++i)
#pragma unroll
          for (int mt = 0; mt < 4; ++mt)
            acc[mt][i][e] = __builtin_amdgcn_mfma_f32_16x16x32_bf16(A[mt], Bf[i], acc[mt][i][e], 0, 0, 0);
      }
      if (ks < 7) {
#pragma unroll
        for (int i = 0; i < 5; ++i) Bf[i] = Bn[i];
      }
    }
  } else {                           // 4 tiles {4w..4w+3}, no dup
    const int t0 = 4 * w;
    sh8 Bf[4];
#pragma unroll
    for (int i = 0; i < 4; ++i)
      Bf[i] = *(const sh8*)(w2f + ((0 * 17 + t0 + i) * 64 + lane) * 8);
#pragma unroll
    for (int ks = 0; ks < 8; ++ks) {
      sh8 Bn[4];
      if (ks < 7) {
#pragma unroll
        for (int i = 0; i < 4; ++i)
          Bn[i] = *(const sh8*)(w2f + (((ks + 1) * 17 + t0 + i) * 64 + lane) * 8);
      }
#pragma unroll
      for (int e = 0; e < 2; ++e) {
        sh8 A[4];
#pragma unroll
        for (int mt = 0; mt < 4; ++mt)
          A[mt] = *(const sh8*)(&hlds[e][((mt * 8 + ks) * 64 + lane) * 8]);
#pragma unroll
        for (int i = 0; i < 4; ++i)
#pragma unroll
          for (int mt = 0; mt < 4; ++mt)
            acc[mt][i][e] = __builtin_amdgcn_mfma_f32_16x16x32_bf16(A[mt], Bf[i], acc[mt][i][e], 0, 0, 0);
      }
      if (ks < 7) {
#pragma unroll
        for (int i = 0; i < 4; ++i) Bf[i] = Bn[i];
      }
    }
  }

  // ---- phase 3 ----
  const float ninv[2] = {ninvp[0] + ninvp[1], ninvp[2] + ninvp[3]};
#pragma unroll
  for (int i = 0; i < 5; ++i) {
    if (i == 4 && w != 0) continue;          // 5th tile only on wave 0
    const int t = (i < 4) ? 4 * w + i : 16;
    const int col = t * 16 + m;              // 0..271
    const float b2c = (col < EOUT) ? b2[col] : 0.f;
    const float rb2 = fmaxf(b2c, 0.f);
#pragma unroll
    for (int e = 0; e < 2; ++e) {
      float ssum = 0.f;
#pragma unroll
      for (int mt = 0; mt < 4; ++mt)
#pragma unroll
        for (int r = 0; r < 4; ++r)
          ssum += fmaxf(acc[mt][i][e][r] + b2c, 0.f);
      ssum += __shfl_xor(ssum, 16, 64);
      ssum += __shfl_xor(ssum, 32, 64);
      ssum -= ninv[e] * rb2;                 // pad cols: b2c=0 -> writes 0
      if (q == 0)
        so288[(b0 + e) * XPAD + CAR + col] = ssum;
    }
  }
  if (w == 1 || w == 2) {                    // self-state + tail pad per be
    size_t rr = b0 + (w - 1); if (rr >= (size_t)B) rr = B - 1;
    if (lane < CAR)       so288[rr * XPAD + lane] = s[rr * SROW + lane];
    else if (lane < 16)   so288[rr * XPAD + 280 + (lane - 8)] = 0.f;
  }
}

// ---------------------------------------------------------------------------
// K2: Q-head, MFMA. 4 waves, 32 batch rows per block (R5 version, ~13 us).
// ---------------------------------------------------------------------------
__global__ __launch_bounds__(256, 2)
void k_q(const float* __restrict__ so288, const short* __restrict__ w3f,
         const float* __restrict__ Qb1, const short* __restrict__ wq2f,
         const float* __restrict__ Qb2, float* __restrict__ out, int B) {
  __shared__ __align__(16) short xf[2 * 9 * 64 * 8];  // 36 KB, [mt][ks][lane][j]
  __shared__ __align__(16) float H[32 * 260];          // 33.3 KB
  const int tid = threadIdx.x;
  const int w = tid >> 6, lane = tid & 63;
  const int q = lane >> 4, m = lane & 15;
  const int b0 = blockIdx.x * 32;

  // ---- stage X ----
#pragma unroll
  for (int it = 0; it < 5; ++it) {
    int sidx = tid + it * 256;               // = (mt*9+ks)*64 + l
    if (sidx < 1152) {
      int mt = sidx / 576, rem = sidx % 576;
      int ks = rem >> 6, l = rem & 63;
      int lq = l >> 4, lm = l & 15;
      int row = b0 + mt * 16 + lm; if (row >= B) row = B - 1;
      const float* xp = so288 + (size_t)row * XPAD + ks * 32 + lq * 8;
      float4 xa = ((const float4*)xp)[0], xb = ((const float4*)xp)[1];
      int4 t = {(int)f2bf2(xa.x, xa.y), (int)f2bf2(xa.z, xa.w),
                (int)f2bf2(xb.x, xb.y), (int)f2bf2(xb.z, xb.w)};
      *(int4*)(xf + sidx * 8) = t;
    }
  }
  __syncthreads();

  // ---- GEMM1: X(32x288) @ Qw1 -> H ----
  f32x4 acc1[2][4];
#pragma unroll
  for (int mt = 0; mt < 2; ++mt)
#pragma unroll
    for (int i = 0; i < 4; ++i) {
      f32x4 z = {0.f, 0.f, 0.f, 0.f};
      acc1[mt][i] = z;
    }
#pragma unroll
  for (int ks = 0; ks < 9; ++ks) {
    sh8 A0 = *(const sh8*)(xf + ((0 * 9 + ks) * 64 + lane) * 8);
    sh8 A1 = *(const sh8*)(xf + ((1 * 9 + ks) * 64 + lane) * 8);
#pragma unroll
    for (int i = 0; i < 4; ++i) {
      sh8 Bf = *(const sh8*)(w3f + ((ks * 16 + 4 * w + i) * 64 + lane) * 8);
      acc1[0][i] = __builtin_amdgcn_mfma_f32_16x16x32_bf16(A0, Bf, acc1[0][i], 0, 0, 0);
      acc1[1][i] = __builtin_amdgcn_mfma_f32_16x16x32_bf16(A1, Bf, acc1[1][i], 0, 0, 0);
    }
  }
#pragma unroll
  for (int i = 0; i < 4; ++i) {
    const int hcol = (4 * w + i) * 16 + m;
    const float bq = Qb1[hcol];
#pragma unroll
    for (int mt = 0; mt < 2; ++mt)
#pragma unroll
      for (int r = 0; r < 4; ++r)
        H[(mt * 16 + q * 4 + r) * 260 + hcol] = fmaxf(acc1[mt][i][r] + bq, 0.f);
  }
  __syncthreads();

  // ---- GEMM2: H(32x256) @ Qw2 -> out ----
  const int mt2 = w >> 1, nt2 = w & 1;
  f32x4 acc2 = {0.f, 0.f, 0.f, 0.f};
#pragma unroll
  for (int ks = 0; ks < 8; ++ks) {
    const float* hp = H + (mt2 * 16 + m) * 260 + ks * 32 + q * 8;
    float4 ha = ((const float4*)hp)[0], hb = ((const float4*)hp)[1];
    int4 t = {(int)f2bf2(ha.x, ha.y), (int)f2bf2(ha.z, ha.w),
              (int)f2bf2(hb.x, hb.y), (int)f2bf2(hb.z, hb.w)};
    sh8 A2 = __builtin_bit_cast(sh8, t);
    sh8 Bf = *(const sh8*)(wq2f + ((ks * 2 + nt2) * 64 + lane) * 8);
    acc2 = __builtin_amdgcn_mfma_f32_16x16x32_bf16(A2, Bf, acc2, 0, 0, 0);
  }
  const int act = nt2 * 16 + m;
  if (act < ADIM) {
    const float bq = Qb2[act];
#pragma unroll
    for (int r = 0; r < 4; ++r) {
      const int row = b0 + mt2 * 16 + q * 4 + r;
      if (row < B) out[(size_t)row * ADIM + act] = acc2[r] + bq;
    }
  }
}

extern "C" void kernel_launch(void* const* d_in, const int* in_sizes, int n_in,
                              void* d_out, int out_size, void* d_ws, size_t ws_size,
                              hipStream_t stream) {
  const float* s   = (const float*)d_in[0];
  const float* W1  = (const float*)d_in[1];
  const float* b1  = (const float*)d_in[2];
  const float* W2  = (const float*)d_in[3];
  const float* b2  = (const float*)d_in[4];
  const float* Qw1 = (const float*)d_in[5];
  const float* Qb1 = (const float*)d_in[6];
  const float* Qw2 = (const float*)d_in[7];
  const float* Qb2 = (const float*)d_in[8];
  float* out = (float*)d_out;
  const int B = in_sizes[0] / SROW;

  // ws: [so288: B*288 f32][w1f 8192][w2f 69632][w3f 73728][wq2f 8192] bf16
  char* wsb = (char*)d_ws;
  float* so288 = (float*)wsb;
  size_t off = (size_t)B * XPAD * sizeof(float);
  short* w1f  = (short*)(wsb + off);            off += 8192 * 2;
  short* w2f  = (short*)(wsb + off);            off += 69632 * 2;
  short* w3f  = (short*)(wsb + off);            off += 73728 * 2;
  short* wq2f = (short*)(wsb + off);

  const int prep_elems = 8192 + 69632 + 73728 + 8192;
  k_prep<<<(prep_elems + 255) / 256, 256, 0, stream>>>(W1, b1, W2, Qw1, Qw2,
                                                       w1f, w2f, w3f, wq2f);
  k_enc<<<(B + 1) / 2, 256, 0, stream>>>(s, w1f, w2f, b2, so288, B);
  k_q<<<(B + 31) / 32, 256, 0, stream>>>(so288, w3f, Qb1, wq2f, Qb2, out, B);
}